// Round 1
// baseline (5373.562 us; speedup 1.0000x reference)
//
#include <hip/hip_runtime.h>
#include <math.h>
#include <float.h>

#define NQ     256
#define NBANK  50000
#define DIMS   4096
#define DIMD   2048
#define TOPK   9
#define BN     64
#define BK     16
#define NCHUNK ((NBANK + BN - 1) / BN)   // 782

// ---------------------------------------------------------------------------
// Per-row inverse L2 norm of a [NBANK, D] bank.
__global__ __launch_bounds__(256) void rnorm_kernel(const float* __restrict__ bank,
                                                    int D, float* __restrict__ rn) {
    int row = blockIdx.x;
    const float4* p = (const float4*)(bank + (size_t)row * D);
    int nd4 = D >> 2;
    float s = 0.f;
    for (int i = threadIdx.x; i < nd4; i += 256) {
        float4 v = p[i];
        s += v.x * v.x + v.y * v.y + v.z * v.z + v.w * v.w;
    }
    #pragma unroll
    for (int off = 32; off; off >>= 1) s += __shfl_xor(s, off);
    __shared__ float red[4];
    int lane = threadIdx.x & 63, w = threadIdx.x >> 6;
    if (lane == 0) red[w] = s;
    __syncthreads();
    if (threadIdx.x == 0) {
        float t = red[0] + red[1] + red[2] + red[3];
        rn[row] = 1.0f / sqrtf(t);
    }
}

// ---------------------------------------------------------------------------
// GEMM: scores[q, n] = dot(Q[q,:], bank[n,:]) * rn[n] for a BN-chunk of n,
// all 256 queries per block. Epilogue: per-query top-9 over the 64 n in this
// chunk -> partial lists in ws.
__global__ __launch_bounds__(256) void gemm_topk_kernel(
    const float* __restrict__ Q,      // [NQ, D]
    const float* __restrict__ bank,   // [NBANK, D]
    const float* __restrict__ rn,     // [NBANK]
    int D,
    float* __restrict__ pvals,        // [NCHUNK, NQ, TOPK]
    int*   __restrict__ pidx)
{
    __shared__ float As[BK][260];     // +4 pad: 16B-aligned rows, conflict-free
    __shared__ float Bs[BK][68];
    __shared__ float Rn[BN];
    __shared__ float Sb[64][BN + 1];

    const int tid = threadIdx.x;
    const int tx  = tid & 7;          // n-dir (8 threads x 8 n)
    const int ty  = tid >> 3;         // q-dir (32 threads x 8 q)
    const int n0  = blockIdx.x * BN;

    if (tid < BN) {
        int n = n0 + tid;
        Rn[tid] = (n < NBANK) ? rn[n] : 0.f;
    }

    float acc[8][8];
    #pragma unroll
    for (int i = 0; i < 8; ++i)
        #pragma unroll
        for (int j = 0; j < 8; ++j) acc[i][j] = 0.f;

    const int na = tid >> 2;              // 0..63: bank row within tile
    const int ki = (tid & 3) << 2;        // 0,4,8,12: k offset within BK
    const bool nvalid = (n0 + na) < NBANK;
    const float* brow = bank + (size_t)(nvalid ? (n0 + na) : 0) * D;
    const float* arow = Q + (size_t)tid * D;

    for (int k0 = 0; k0 < D; k0 += BK) {
        // Global loads first (each thread: one full 64B line of A, 16B of B)
        float4 a4[4];
        const float4* ap = (const float4*)(arow + k0);
        #pragma unroll
        for (int u = 0; u < 4; ++u) a4[u] = ap[u];
        float4 b4 = make_float4(0.f, 0.f, 0.f, 0.f);
        if (nvalid) b4 = *(const float4*)(brow + k0 + ki);

        __syncthreads();   // previous iteration's LDS reads complete
        #pragma unroll
        for (int u = 0; u < 4; ++u) {
            As[4 * u + 0][tid] = a4[u].x;
            As[4 * u + 1][tid] = a4[u].y;
            As[4 * u + 2][tid] = a4[u].z;
            As[4 * u + 3][tid] = a4[u].w;
        }
        Bs[ki + 0][na] = b4.x;
        Bs[ki + 1][na] = b4.y;
        Bs[ki + 2][na] = b4.z;
        Bs[ki + 3][na] = b4.w;
        __syncthreads();

        #pragma unroll
        for (int k = 0; k < BK; ++k) {
            float a[8], b[8];
            *(float4*)&a[0] = *(const float4*)&As[k][ty * 8];
            *(float4*)&a[4] = *(const float4*)&As[k][ty * 8 + 4];
            *(float4*)&b[0] = *(const float4*)&Bs[k][tx * 8];
            *(float4*)&b[4] = *(const float4*)&Bs[k][tx * 8 + 4];
            #pragma unroll
            for (int i = 0; i < 8; ++i)
                #pragma unroll
                for (int j = 0; j < 8; ++j)
                    acc[i][j] = fmaf(a[i], b[j], acc[i][j]);
        }
    }
    __syncthreads();

    // Epilogue: 4 groups of 64 queries; scale by Rn, top-9 per query row.
    for (int g = 0; g < 4; ++g) {
        if ((ty >> 3) == g) {
            int qr = (ty & 7) * 8;
            #pragma unroll
            for (int i = 0; i < 8; ++i)
                #pragma unroll
                for (int j = 0; j < 8; ++j) {
                    int nl = tx * 8 + j;
                    float v = (n0 + nl < NBANK) ? acc[i][j] * Rn[nl] : -INFINITY;
                    Sb[qr + i][nl] = v;
                }
        }
        __syncthreads();
        if (tid < 64) {
            float tv[TOPK]; int ti[TOPK];
            #pragma unroll
            for (int j = 0; j < TOPK; ++j) { tv[j] = -INFINITY; ti[j] = 0x7fffffff; }
            for (int n = 0; n < BN; ++n) {       // ascending n => lowest-index tie wins
                float v = Sb[tid][n];
                if (v > tv[TOPK - 1]) {
                    tv[TOPK - 1] = v; ti[TOPK - 1] = n0 + n;
                    #pragma unroll
                    for (int j = TOPK - 1; j > 0; --j) {
                        bool better = (tv[j] > tv[j - 1]) ||
                                      (tv[j] == tv[j - 1] && ti[j] < ti[j - 1]);
                        if (better) {
                            float fv = tv[j]; tv[j] = tv[j - 1]; tv[j - 1] = fv;
                            int   fi = ti[j]; ti[j] = ti[j - 1]; ti[j - 1] = fi;
                        }
                    }
                }
            }
            int q = g * 64 + tid;
            size_t base = ((size_t)blockIdx.x * NQ + q) * TOPK;
            #pragma unroll
            for (int j = 0; j < TOPK; ++j) { pvals[base + j] = tv[j]; pidx[base + j] = ti[j]; }
        }
        __syncthreads();
    }
}

// ---------------------------------------------------------------------------
// Merge NCHUNK partial top-9 lists per query -> global top-9 -> sum of metrics.
__global__ __launch_bounds__(256) void merge_kernel(
    const float* __restrict__ pvals, const int* __restrict__ pidx,
    const float* __restrict__ metrics, float* __restrict__ osum)
{
    const int q   = blockIdx.x;
    const int tid = threadIdx.x;

    float tv[TOPK]; int ti[TOPK];
    #pragma unroll
    for (int j = 0; j < TOPK; ++j) { tv[j] = -INFINITY; ti[j] = 0x7fffffff; }

    const int total = NCHUNK * TOPK;
    for (int e = tid; e < total; e += 256) {
        int c = e / TOPK, j = e - c * TOPK;
        size_t a = ((size_t)c * NQ + q) * TOPK + j;
        float v  = pvals[a];
        int  idx = pidx[a];
        bool better = (v > tv[TOPK - 1]) || (v == tv[TOPK - 1] && idx < ti[TOPK - 1]);
        if (better) {
            tv[TOPK - 1] = v; ti[TOPK - 1] = idx;
            #pragma unroll
            for (int jj = TOPK - 1; jj > 0; --jj) {
                bool b2 = (tv[jj] > tv[jj - 1]) ||
                          (tv[jj] == tv[jj - 1] && ti[jj] < ti[jj - 1]);
                if (b2) {
                    float fv = tv[jj]; tv[jj] = tv[jj - 1]; tv[jj - 1] = fv;
                    int   fi = ti[jj]; ti[jj] = ti[jj - 1]; ti[jj - 1] = fi;
                }
            }
        }
    }

    // Wave-level pop-merge: 9 iterations of argmax-with-tiebreak over 64 lanes.
    __shared__ float wv[4][TOPK];
    __shared__ int   wi[4][TOPK];
    int lane = tid & 63, w = tid >> 6;
    int p = 0;
    for (int it = 0; it < TOPK; ++it) {
        float cv = (p < TOPK) ? tv[p] : -INFINITY;
        int   ci = (p < TOPK) ? ti[p] : 0x7fffffff;
        float bv = cv; int bi = ci;
        #pragma unroll
        for (int off = 32; off; off >>= 1) {
            float ov = __shfl_xor(bv, off);
            int   oi = __shfl_xor(bi, off);
            if (ov > bv || (ov == bv && oi < bi)) { bv = ov; bi = oi; }
        }
        if (cv == bv && ci == bi) p++;   // unique idx => exactly one lane pops
        if (lane == 0) { wv[w][it] = bv; wi[w][it] = bi; }
    }
    __syncthreads();

    if (tid == 0) {
        int ptr[4] = {0, 0, 0, 0};
        float s = 0.f;
        for (int it = 0; it < TOPK; ++it) {
            float bv = -INFINITY; int bi = 0x7fffffff; int bw = 0;
            #pragma unroll
            for (int w2 = 0; w2 < 4; ++w2) {
                if (ptr[w2] < TOPK) {
                    float v  = wv[w2][ptr[w2]];
                    int   i2 = wi[w2][ptr[w2]];
                    if (v > bv || (v == bv && i2 < bi)) { bv = v; bi = i2; bw = w2; }
                }
            }
            ptr[bw]++;
            s += metrics[bi];
        }
        osum[q] = s;
    }
}

// ---------------------------------------------------------------------------
__global__ void final_kernel(const float* __restrict__ s0, const float* __restrict__ s1,
                             float* __restrict__ out) {
    int b = threadIdx.x;
    out[b] = (s0[b] + s1[b]) * (1.0f / (2.0f * TOPK));
}

// ---------------------------------------------------------------------------
extern "C" void kernel_launch(void* const* d_in, const int* in_sizes, int n_in,
                              void* d_out, int out_size, void* d_ws, size_t ws_size,
                              hipStream_t stream) {
    const float* f_content  = (const float*)d_in[0];   // [256, 4096]
    const float* f_dist     = (const float*)d_in[1];   // [256, 2048]
    const float* sem_bank   = (const float*)d_in[2];   // [50000, 4096]
    const float* dst_bank   = (const float*)d_in[3];   // [50000, 2048]
    const float* metrics    = (const float*)d_in[4];   // [50000]
    // d_in[5] = K (always 9 in this problem; TOPK hard-coded)

    float* rn_s  = (float*)d_ws;                            // 50000
    float* rn_d  = rn_s + NBANK;                            // 50000
    float* sum_s = rn_d + NBANK;                            // 256
    float* sum_d = sum_s + NQ;                              // 256
    float* pvals = sum_d + NQ;                              // NCHUNK*NQ*TOPK
    int*   pidx  = (int*)(pvals + (size_t)NCHUNK * NQ * TOPK);

    rnorm_kernel<<<NBANK, 256, 0, stream>>>(sem_bank, DIMS, rn_s);
    rnorm_kernel<<<NBANK, 256, 0, stream>>>(dst_bank, DIMD, rn_d);

    gemm_topk_kernel<<<NCHUNK, 256, 0, stream>>>(f_content, sem_bank, rn_s, DIMS, pvals, pidx);
    merge_kernel<<<NQ, 256, 0, stream>>>(pvals, pidx, metrics, sum_s);

    gemm_topk_kernel<<<NCHUNK, 256, 0, stream>>>(f_dist, dst_bank, rn_d, DIMD, pvals, pidx);
    merge_kernel<<<NQ, 256, 0, stream>>>(pvals, pidx, metrics, sum_d);

    final_kernel<<<1, 256, 0, stream>>>(sum_s, sum_d, (float*)d_out);
}